// Round 1
// baseline (245.529 us; speedup 1.0000x reference)
//
#include <hip/hip_runtime.h>
#include <hip/hip_bf16.h>
#include <stdint.h>

#define SEQ 4096
#define DIM 1024

typedef __attribute__((ext_vector_type(8))) __bf16 bf16x8;
typedef __attribute__((ext_vector_type(4))) float f32x4;
typedef __attribute__((ext_vector_type(8))) unsigned short u16x8;

__device__ __forceinline__ unsigned short f2bf(float f) {
  unsigned int u = __float_as_uint(f);
  u = (u + 0x7FFFu + ((u >> 16) & 1u)) >> 16;
  return (unsigned short)u;
}

// ---------------- f32 -> bf16 convert (8 elems/thread) ----------------
__global__ void __launch_bounds__(256) cvt_kernel(const float* __restrict__ src,
                                                  unsigned short* __restrict__ dst) {
  size_t i = (size_t)(blockIdx.x * 256 + threadIdx.x) * 8;
  float4 a = *reinterpret_cast<const float4*>(src + i);
  float4 b = *reinterpret_cast<const float4*>(src + i + 4);
  u16x8 o;
  o[0] = f2bf(a.x); o[1] = f2bf(a.y); o[2] = f2bf(a.z); o[3] = f2bf(a.w);
  o[4] = f2bf(b.x); o[5] = f2bf(b.y); o[6] = f2bf(b.z); o[7] = f2bf(b.w);
  *reinterpret_cast<u16x8*>(dst + i) = o;
}

// ---------------- bf16 transpose: in[SEQ][DIM] -> out[DIM][SEQ] ----------------
__global__ void __launch_bounds__(256) transpose_bf16(const unsigned short* __restrict__ in,
                                                      unsigned short* __restrict__ out) {
  __shared__ unsigned short t[64][72];
  const int bi = blockIdx.x;  // column tile of input (16)
  const int bj = blockIdx.y;  // row tile of input (64)
  const int tid = threadIdx.x;
  #pragma unroll
  for (int i = 0; i < 2; ++i) {
    int v = tid + i * 256;
    int r = v >> 3, c = (v & 7) * 8;
    u16x8 d = *reinterpret_cast<const u16x8*>(in + (size_t)(bj * 64 + r) * DIM + bi * 64 + c);
    #pragma unroll
    for (int e = 0; e < 8; ++e) t[r][c + e] = d[e];
  }
  __syncthreads();
  #pragma unroll
  for (int i = 0; i < 2; ++i) {
    int v = tid + i * 256;
    int r = v >> 3, c = (v & 7) * 8;
    u16x8 d;
    #pragma unroll
    for (int e = 0; e < 8; ++e) d[e] = t[c + e][r];
    *reinterpret_cast<u16x8*>(out + (size_t)(bi * 64 + r) * SEQ + bj * 64 + c) = d;
  }
}

// ---------------- NT GEMM: C[m][n] = scale * sum_k A[m][k]*B[n][k] ----------------
// 128x128 tile, BK=32, 4 waves (2x2), each wave 64x64 via 4x4 frags of 16x16x32.
// MODE: 0 = plain, 1 = qk^t (skip tiles with tc>tr), 2 = pv (K limited to (tr+1)*128)
template <int OUT_BF16, int MODE>
__global__ void __launch_bounds__(256) gemm_nt(const unsigned short* __restrict__ A,
                                               const unsigned short* __restrict__ B,
                                               void* __restrict__ C,
                                               int lda, int ldb, int ldc, int K, float scale) {
  const int tc = blockIdx.x, tr = blockIdx.y;
  if (MODE == 1 && tc > tr) return;
  int kTiles = K >> 5;
  if (MODE == 2) kTiles = (tr + 1) * 4;

  __shared__ __align__(16) unsigned short As[128 * 32];
  __shared__ __align__(16) unsigned short Bs[128 * 32];

  const int tid = threadIdx.x;
  const int lane = tid & 63;
  const int wid = tid >> 6;
  const int wr = wid >> 1, wc = wid & 1;
  const int l15 = lane & 15;
  const int kfrag = (lane >> 4) * 8;

  f32x4 acc[4][4];
  #pragma unroll
  for (int m = 0; m < 4; ++m)
    #pragma unroll
    for (int n = 0; n < 4; ++n)
      acc[m][n] = (f32x4){0.f, 0.f, 0.f, 0.f};

  const unsigned short* Abase = A + (size_t)tr * 128 * lda;
  const unsigned short* Bbase = B + (size_t)tc * 128 * ldb;

  for (int kt = 0; kt < kTiles; ++kt) {
    const int k0 = kt * 32;
    #pragma unroll
    for (int i = 0; i < 2; ++i) {
      const int c = tid + i * 256;
      const int row = c >> 2;
      const int kc = (c & 3) * 8;
      const unsigned short* ga = Abase + (size_t)row * lda + (k0 + kc);
      const unsigned short* gb = Bbase + (size_t)row * ldb + (k0 + kc);
      __builtin_amdgcn_global_load_lds(
          (const __attribute__((address_space(1))) unsigned int*)ga,
          (__attribute__((address_space(3))) unsigned int*)(As + c * 8), 16, 0, 0);
      __builtin_amdgcn_global_load_lds(
          (const __attribute__((address_space(1))) unsigned int*)gb,
          (__attribute__((address_space(3))) unsigned int*)(Bs + c * 8), 16, 0, 0);
    }
    __syncthreads();

    bf16x8 af[4], bfr[4];
    #pragma unroll
    for (int m = 0; m < 4; ++m)
      af[m] = *reinterpret_cast<const bf16x8*>(As + (wr * 64 + m * 16 + l15) * 32 + kfrag);
    #pragma unroll
    for (int n = 0; n < 4; ++n)
      bfr[n] = *reinterpret_cast<const bf16x8*>(Bs + (wc * 64 + n * 16 + l15) * 32 + kfrag);

    #pragma unroll
    for (int m = 0; m < 4; ++m)
      #pragma unroll
      for (int n = 0; n < 4; ++n)
        acc[m][n] = __builtin_amdgcn_mfma_f32_16x16x32_bf16(af[m], bfr[n], acc[m][n], 0, 0, 0);
    __syncthreads();
  }

  const int rbase = tr * 128 + wr * 64 + (lane >> 4) * 4;
  const int cbase = tc * 128 + wc * 64 + l15;
  #pragma unroll
  for (int m = 0; m < 4; ++m)
    #pragma unroll
    for (int n = 0; n < 4; ++n)
      #pragma unroll
      for (int i = 0; i < 4; ++i) {
        const int row = rbase + m * 16 + i;
        const int col = cbase + n * 16;
        float v = acc[m][n][i] * scale;
        if (OUT_BF16)
          ((unsigned short*)C)[(size_t)row * ldc + col] = f2bf(v);
        else
          ((float*)C)[(size_t)row * ldc + col] = v;
      }
}

// ---------------- in-place causal row softmax over S[SEQ][SEQ] bf16 ----------------
__global__ void __launch_bounds__(256) softmax_causal(unsigned short* __restrict__ S) {
  const int row = blockIdx.x;
  unsigned short* Srow = S + (size_t)row * SEQ;
  const int tid = threadIdx.x;
  const int lane = tid & 63, wid = tid >> 6;

  float vals[16];
  #pragma unroll
  for (int i = 0; i < 2; ++i) {
    const int v = tid + i * 256;
    const uint4 w = *reinterpret_cast<const uint4*>(Srow + v * 8);
    const unsigned int wb[4] = {w.x, w.y, w.z, w.w};
    #pragma unroll
    for (int e = 0; e < 4; ++e) {
      vals[i * 8 + 2 * e]     = __uint_as_float(wb[e] << 16);
      vals[i * 8 + 2 * e + 1] = __uint_as_float(wb[e] & 0xFFFF0000u);
    }
  }

  float m = -1e30f;
  #pragma unroll
  for (int i = 0; i < 2; ++i)
    #pragma unroll
    for (int e = 0; e < 8; ++e) {
      int j = (tid + i * 256) * 8 + e;
      if (j <= row) m = fmaxf(m, vals[i * 8 + e]);
    }
  #pragma unroll
  for (int off = 32; off > 0; off >>= 1) m = fmaxf(m, __shfl_xor(m, off));
  __shared__ float redm[4], reds[4];
  if (lane == 0) redm[wid] = m;
  __syncthreads();
  m = fmaxf(fmaxf(redm[0], redm[1]), fmaxf(redm[2], redm[3]));

  float s = 0.f;
  float ev[16];
  #pragma unroll
  for (int i = 0; i < 2; ++i)
    #pragma unroll
    for (int e = 0; e < 8; ++e) {
      int j = (tid + i * 256) * 8 + e;
      float ex = (j <= row) ? __expf(vals[i * 8 + e] - m) : 0.f;
      ev[i * 8 + e] = ex;
      s += ex;
    }
  #pragma unroll
  for (int off = 32; off > 0; off >>= 1) s += __shfl_xor(s, off);
  if (lane == 0) reds[wid] = s;
  __syncthreads();
  s = reds[0] + reds[1] + reds[2] + reds[3];
  const float inv = 1.f / s;

  #pragma unroll
  for (int i = 0; i < 2; ++i) {
    u16x8 o;
    #pragma unroll
    for (int e = 0; e < 8; ++e) o[e] = f2bf(ev[i * 8 + e] * inv);
    *reinterpret_cast<u16x8*>(Srow + (tid + i * 256) * 8) = o;
  }
}

extern "C" void kernel_launch(void* const* d_in, const int* in_sizes, int n_in,
                              void* d_out, int out_size, void* d_ws, size_t ws_size,
                              hipStream_t stream) {
  const float* x  = (const float*)d_in[0];
  const float* Wq = (const float*)d_in[1];
  const float* Wk = (const float*)d_in[2];
  const float* Wv = (const float*)d_in[3];
  float* out = (float*)d_out;

  char* ws = (char*)d_ws;
  const size_t MB = 1u << 20;
  unsigned short* xb  = (unsigned short*)(ws + 0 * MB);   // 8 MB
  unsigned short* wqb = (unsigned short*)(ws + 8 * MB);   // 2 MB
  unsigned short* wkb = (unsigned short*)(ws + 10 * MB);  // 2 MB
  unsigned short* wvb = (unsigned short*)(ws + 12 * MB);  // 2 MB
  unsigned short* qb  = (unsigned short*)(ws + 14 * MB);  // 8 MB
  unsigned short* kb  = (unsigned short*)(ws + 22 * MB);  // 8 MB
  unsigned short* vb  = (unsigned short*)(ws + 30 * MB);  // 8 MB
  unsigned short* vt  = (unsigned short*)(ws + 38 * MB);  // 8 MB
  unsigned short* S   = (unsigned short*)(ws + 46 * MB);  // 32 MB (-> P in place)

  cvt_kernel<<<SEQ * DIM / 2048, 256, 0, stream>>>(x, xb);
  cvt_kernel<<<DIM * DIM / 2048, 256, 0, stream>>>(Wq, wqb);
  cvt_kernel<<<DIM * DIM / 2048, 256, 0, stream>>>(Wk, wkb);
  cvt_kernel<<<DIM * DIM / 2048, 256, 0, stream>>>(Wv, wvb);

  dim3 gproj(DIM / 128, SEQ / 128);
  gemm_nt<1, 0><<<gproj, 256, 0, stream>>>(xb, wqb, qb, DIM, DIM, DIM, DIM, 1.0f);
  gemm_nt<1, 0><<<gproj, 256, 0, stream>>>(xb, wkb, kb, DIM, DIM, DIM, DIM, 1.0f);
  gemm_nt<1, 0><<<gproj, 256, 0, stream>>>(xb, wvb, vb, DIM, DIM, DIM, DIM, 1.0f);

  transpose_bf16<<<dim3(DIM / 64, SEQ / 64), 256, 0, stream>>>(vb, vt);

  gemm_nt<1, 1><<<dim3(SEQ / 128, SEQ / 128), 256, 0, stream>>>(qb, kb, S, DIM, DIM, SEQ, DIM, 0.03125f);

  softmax_causal<<<SEQ, 256, 0, stream>>>(S);

  gemm_nt<0, 2><<<dim3(DIM / 128, SEQ / 128), 256, 0, stream>>>(S, vt, out, SEQ, SEQ, DIM, SEQ, 1.0f);
}

// Round 2
// 181.591 us; speedup vs baseline: 1.3521x; 1.3521x over previous
//
#include <hip/hip_runtime.h>
#include <hip/hip_bf16.h>
#include <stdint.h>

#define SEQ 4096
#define DIM 1024

typedef __attribute__((ext_vector_type(8))) __bf16 bf16x8;
typedef __attribute__((ext_vector_type(4))) float f32x4;
typedef __attribute__((ext_vector_type(8))) unsigned short u16x8;

__device__ __forceinline__ unsigned short f2bf(float f) {
  unsigned int u = __float_as_uint(f);
  u = (u + 0x7FFFu + ((u >> 16) & 1u)) >> 16;
  return (unsigned short)u;
}

// XOR swizzle: spreads the 8 16B-slots of each 128B LDS row across banks.
__device__ __forceinline__ int swz(int o) { return o ^ (((o >> 7) & 7) << 4); }

template <int N> __device__ __forceinline__ void wait_vm() {
  if constexpr (N == 0) asm volatile("s_waitcnt vmcnt(0)" ::: "memory");
  else if constexpr (N == 6) asm volatile("s_waitcnt vmcnt(6)" ::: "memory");
  else if constexpr (N == 8) asm volatile("s_waitcnt vmcnt(8)" ::: "memory");
}

// ---------------- f32 -> bf16 convert (8 elems/thread) ----------------
__global__ void __launch_bounds__(256) cvt_kernel(const float* __restrict__ src,
                                                  unsigned short* __restrict__ dst) {
  size_t i = (size_t)(blockIdx.x * 256 + threadIdx.x) * 8;
  float4 a = *reinterpret_cast<const float4*>(src + i);
  float4 b = *reinterpret_cast<const float4*>(src + i + 4);
  u16x8 o;
  o[0] = f2bf(a.x); o[1] = f2bf(a.y); o[2] = f2bf(a.z); o[3] = f2bf(a.w);
  o[4] = f2bf(b.x); o[5] = f2bf(b.y); o[6] = f2bf(b.z); o[7] = f2bf(b.w);
  *reinterpret_cast<u16x8*>(dst + i) = o;
}

// ---------------- NT GEMM: C[m][n] = scale * sum_k A[m][k]*B[n][k] ----------------
// BM x 128 tile, BK=64, 4 waves (2x2), 2-phase double-buffered pipeline with
// counted vmcnt (T3/T4), XOR-swizzled LDS (T2, rule-21 both-sides pattern).
// MODE: 0 = plain, 1 = qk^t (skip tc>tr), 2 = pv (row-reversed grid, K=(tr+1)*64)
template <int BM, int OUT_BF16, int MODE>
__global__ void __launch_bounds__(256) gemm_nt(const unsigned short* __restrict__ A,
                                               const unsigned short* __restrict__ B,
                                               void* __restrict__ C,
                                               int lda, int ldb, int ldc, int K, float scale) {
  constexpr int FM = BM / 32;   // m-fragments per wave
  constexpr int NLA = BM / 32;  // A global_load_lds per thread per tile
  constexpr int NL = NLA + 4;   // total loads in flight for one tile

  int tc = blockIdx.x, tr = blockIdx.y;
  if (MODE == 1 && tc > tr) return;
  if (MODE == 2) tr = gridDim.y - 1 - tr;  // heavy rows dispatch first
  const int nt = (MODE == 2) ? (tr + 1) : (K >> 6);

  __shared__ __align__(16) unsigned short As[2][BM * 64];
  __shared__ __align__(16) unsigned short Bs[2][128 * 64];

  const int tid = threadIdx.x;
  const int lane = tid & 63;
  const int wid = tid >> 6;
  const int wr = wid >> 1, wc = wid & 1;
  const int l15 = lane & 15;
  const int kq = lane >> 4;

  f32x4 acc[FM][4];
  #pragma unroll
  for (int m = 0; m < FM; ++m)
    #pragma unroll
    for (int n = 0; n < 4; ++n)
      acc[m][n] = (f32x4){0.f, 0.f, 0.f, 0.f};

  const unsigned short* Abase = A + (size_t)tr * BM * lda;
  const unsigned short* Bbase = B + (size_t)tc * 128 * ldb;

  auto stage = [&](int buf, int kt) {
    const int k0 = kt << 6;
    #pragma unroll
    for (int i = 0; i < NLA; ++i) {
      const int o = (i * 256 + tid) * 16;
      const int os = swz(o);
      const unsigned short* g = Abase + (size_t)(o >> 7) * lda + k0 + ((os >> 4) & 7) * 8;
      __builtin_amdgcn_global_load_lds(
          (const __attribute__((address_space(1))) unsigned int*)g,
          (__attribute__((address_space(3))) unsigned int*)((char*)&As[buf][0] + o), 16, 0, 0);
    }
    #pragma unroll
    for (int i = 0; i < 4; ++i) {
      const int o = (i * 256 + tid) * 16;
      const int os = swz(o);
      const unsigned short* g = Bbase + (size_t)(o >> 7) * ldb + k0 + ((os >> 4) & 7) * 8;
      __builtin_amdgcn_global_load_lds(
          (const __attribute__((address_space(1))) unsigned int*)g,
          (__attribute__((address_space(3))) unsigned int*)((char*)&Bs[buf][0] + o), 16, 0, 0);
    }
  };

  stage(0, 0);
  int cur = 0;
  for (int kt = 0; kt < nt; ++kt) {
    if (kt + 1 < nt) {
      stage(cur ^ 1, kt + 1);   // issue next tile before waiting on current
      wait_vm<NL>();            // counted: leave next tile's loads in flight
    } else {
      wait_vm<0>();
    }
    __builtin_amdgcn_s_barrier();

    bf16x8 af[FM][2], bv[4][2];
    #pragma unroll
    for (int m = 0; m < FM; ++m)
      #pragma unroll
      for (int ks = 0; ks < 2; ++ks) {
        const int row = wr * (BM / 2) + m * 16 + l15;
        const int o = swz(row * 128 + kq * 16 + ks * 64);
        af[m][ks] = *reinterpret_cast<const bf16x8*>((const char*)&As[cur][0] + o);
      }
    #pragma unroll
    for (int n = 0; n < 4; ++n)
      #pragma unroll
      for (int ks = 0; ks < 2; ++ks) {
        const int row = wc * 64 + n * 16 + l15;
        const int o = swz(row * 128 + kq * 16 + ks * 64);
        bv[n][ks] = *reinterpret_cast<const bf16x8*>((const char*)&Bs[cur][0] + o);
      }
    #pragma unroll
    for (int m = 0; m < FM; ++m)
      #pragma unroll
      for (int n = 0; n < 4; ++n) {
        acc[m][n] = __builtin_amdgcn_mfma_f32_16x16x32_bf16(af[m][0], bv[n][0], acc[m][n], 0, 0, 0);
        acc[m][n] = __builtin_amdgcn_mfma_f32_16x16x32_bf16(af[m][1], bv[n][1], acc[m][n], 0, 0, 0);
      }
    __builtin_amdgcn_s_barrier();
    cur ^= 1;
  }

  const int rbase = tr * BM + wr * (BM / 2) + kq * 4;
  const int cbase = tc * 128 + wc * 64 + l15;
  #pragma unroll
  for (int m = 0; m < FM; ++m)
    #pragma unroll
    for (int n = 0; n < 4; ++n)
      #pragma unroll
      for (int i = 0; i < 4; ++i) {
        const int row = rbase + m * 16 + i;
        const int col = cbase + n * 16;
        float v = acc[m][n][i] * scale;
        if (OUT_BF16)
          ((unsigned short*)C)[(size_t)row * ldc + col] = f2bf(v);
        else
          ((float*)C)[(size_t)row * ldc + col] = v;
      }
}

// ---------------- in-place causal row softmax over S[SEQ][SEQ] bf16 ----------------
__global__ void __launch_bounds__(256) softmax_causal(unsigned short* __restrict__ S) {
  const int row = blockIdx.x;
  unsigned short* Srow = S + (size_t)row * SEQ;
  const int tid = threadIdx.x;
  const int lane = tid & 63, wid = tid >> 6;

  float vals[16];
  #pragma unroll
  for (int i = 0; i < 2; ++i) {
    const int v = tid + i * 256;
    const uint4 w = *reinterpret_cast<const uint4*>(Srow + v * 8);
    const unsigned int wb[4] = {w.x, w.y, w.z, w.w};
    #pragma unroll
    for (int e = 0; e < 4; ++e) {
      vals[i * 8 + 2 * e]     = __uint_as_float(wb[e] << 16);
      vals[i * 8 + 2 * e + 1] = __uint_as_float(wb[e] & 0xFFFF0000u);
    }
  }

  float m = -1e30f;
  #pragma unroll
  for (int i = 0; i < 2; ++i)
    #pragma unroll
    for (int e = 0; e < 8; ++e) {
      int j = (tid + i * 256) * 8 + e;
      if (j <= row) m = fmaxf(m, vals[i * 8 + e]);
    }
  #pragma unroll
  for (int off = 32; off > 0; off >>= 1) m = fmaxf(m, __shfl_xor(m, off));
  __shared__ float redm[4], reds[4];
  if (lane == 0) redm[wid] = m;
  __syncthreads();
  m = fmaxf(fmaxf(redm[0], redm[1]), fmaxf(redm[2], redm[3]));

  float s = 0.f;
  float ev[16];
  #pragma unroll
  for (int i = 0; i < 2; ++i)
    #pragma unroll
    for (int e = 0; e < 8; ++e) {
      int j = (tid + i * 256) * 8 + e;
      float ex = (j <= row) ? __expf(vals[i * 8 + e] - m) : 0.f;
      ev[i * 8 + e] = ex;
      s += ex;
    }
  #pragma unroll
  for (int off = 32; off > 0; off >>= 1) s += __shfl_xor(s, off);
  if (lane == 0) reds[wid] = s;
  __syncthreads();
  s = reds[0] + reds[1] + reds[2] + reds[3];
  const float inv = 1.f / s;

  #pragma unroll
  for (int i = 0; i < 2; ++i) {
    u16x8 o;
    #pragma unroll
    for (int e = 0; e < 8; ++e) o[e] = f2bf(ev[i * 8 + e] * inv);
    *reinterpret_cast<u16x8*>(Srow + (tid + i * 256) * 8) = o;
  }
}

extern "C" void kernel_launch(void* const* d_in, const int* in_sizes, int n_in,
                              void* d_out, int out_size, void* d_ws, size_t ws_size,
                              hipStream_t stream) {
  const float* x  = (const float*)d_in[0];
  const float* Wq = (const float*)d_in[1];
  const float* Wk = (const float*)d_in[2];
  const float* Wv = (const float*)d_in[3];
  float* out = (float*)d_out;

  char* ws = (char*)d_ws;
  const size_t MB = 1u << 20;
  unsigned short* xb  = (unsigned short*)(ws + 0 * MB);   // 8 MB
  unsigned short* wqb = (unsigned short*)(ws + 8 * MB);   // 2 MB
  unsigned short* wkb = (unsigned short*)(ws + 10 * MB);  // 2 MB
  unsigned short* wvb = (unsigned short*)(ws + 12 * MB);  // 2 MB
  unsigned short* qb  = (unsigned short*)(ws + 14 * MB);  // 8 MB
  unsigned short* kb  = (unsigned short*)(ws + 22 * MB);  // 8 MB
  unsigned short* vt  = (unsigned short*)(ws + 30 * MB);  // 8 MB (V^T, [DIM][SEQ])
  unsigned short* S   = (unsigned short*)(ws + 38 * MB);  // 32 MB (-> P in place)

  cvt_kernel<<<SEQ * DIM / 2048, 256, 0, stream>>>(x, xb);
  cvt_kernel<<<DIM * DIM / 2048, 256, 0, stream>>>(Wq, wqb);
  cvt_kernel<<<DIM * DIM / 2048, 256, 0, stream>>>(Wk, wkb);
  cvt_kernel<<<DIM * DIM / 2048, 256, 0, stream>>>(Wv, wvb);

  // Q = x Wq^T, K = x Wk^T  [SEQ][DIM]
  dim3 gproj(DIM / 128, SEQ / 128);
  gemm_nt<128, 1, 0><<<gproj, 256, 0, stream>>>(xb, wqb, qb, DIM, DIM, DIM, DIM, 1.0f);
  gemm_nt<128, 1, 0><<<gproj, 256, 0, stream>>>(xb, wkb, kb, DIM, DIM, DIM, DIM, 1.0f);
  // V^T = Wv x^T directly: [DIM][SEQ], no separate transpose pass
  gemm_nt<128, 1, 0><<<dim3(SEQ / 128, DIM / 128), 256, 0, stream>>>(wvb, xb, vt, DIM, DIM, SEQ, DIM, 1.0f);

  // S = (Q K^T) / 32, causal-skipped tiles
  gemm_nt<128, 1, 1><<<dim3(SEQ / 128, SEQ / 128), 256, 0, stream>>>(qb, kb, S, DIM, DIM, SEQ, DIM, 0.03125f);

  softmax_causal<<<SEQ, 256, 0, stream>>>(S);

  // out = P V  (A=P rows, B=V^T rows), BM=64 row-tiles, causal K-limit
  gemm_nt<64, 0, 2><<<dim3(DIM / 128, SEQ / 64), 256, 0, stream>>>(S, vt, out, SEQ, SEQ, DIM, SEQ, 1.0f);
}

// Round 3
// 145.760 us; speedup vs baseline: 1.6845x; 1.2458x over previous
//
#include <hip/hip_runtime.h>
#include <hip/hip_bf16.h>
#include <stdint.h>

#define SEQ 4096
#define DIM 1024

typedef __attribute__((ext_vector_type(8))) __bf16 bf16x8;
typedef __attribute__((ext_vector_type(4))) float f32x4;
typedef __attribute__((ext_vector_type(8))) unsigned short u16x8;

__device__ __forceinline__ unsigned short f2bf(float f) {
  unsigned int u = __float_as_uint(f);
  u = (u + 0x7FFFu + ((u >> 16) & 1u)) >> 16;
  return (unsigned short)u;
}

// XOR swizzle: spreads the 8 16B-slots of each 128B LDS row across banks.
__device__ __forceinline__ int swz(int o) { return o ^ (((o >> 7) & 7) << 4); }

template <int N> __device__ __forceinline__ void wait_vm() {
  if constexpr (N == 0) asm volatile("s_waitcnt vmcnt(0)" ::: "memory");
  else if constexpr (N == 6) asm volatile("s_waitcnt vmcnt(6)" ::: "memory");
  else if constexpr (N == 8) asm volatile("s_waitcnt vmcnt(8)" ::: "memory");
}

// ---------------- f32 -> bf16 convert (8 elems/thread) ----------------
__global__ void __launch_bounds__(256) cvt_kernel(const float* __restrict__ src,
                                                  unsigned short* __restrict__ dst) {
  size_t i = (size_t)(blockIdx.x * 256 + threadIdx.x) * 8;
  float4 a = *reinterpret_cast<const float4*>(src + i);
  float4 b = *reinterpret_cast<const float4*>(src + i + 4);
  u16x8 o;
  o[0] = f2bf(a.x); o[1] = f2bf(a.y); o[2] = f2bf(a.z); o[3] = f2bf(a.w);
  o[4] = f2bf(b.x); o[5] = f2bf(b.y); o[6] = f2bf(b.z); o[7] = f2bf(b.w);
  *reinterpret_cast<u16x8*>(dst + i) = o;
}

// Convert the three weight matrices in one launch: z=0 Wq, z=1 Wk (stacked), z=2 Wv
__global__ void __launch_bounds__(256) cvt3_kernel(const float* __restrict__ wq,
                                                   const float* __restrict__ wk,
                                                   const float* __restrict__ wv,
                                                   unsigned short* __restrict__ wqk,
                                                   unsigned short* __restrict__ wvb) {
  const int z = blockIdx.y;
  const float* src = (z == 0) ? wq : (z == 1) ? wk : wv;
  unsigned short* dst = (z == 2) ? wvb : wqk + (size_t)z * DIM * DIM;
  size_t i = (size_t)(blockIdx.x * 256 + threadIdx.x) * 8;
  float4 a = *reinterpret_cast<const float4*>(src + i);
  float4 b = *reinterpret_cast<const float4*>(src + i + 4);
  u16x8 o;
  o[0] = f2bf(a.x); o[1] = f2bf(a.y); o[2] = f2bf(a.z); o[3] = f2bf(a.w);
  o[4] = f2bf(b.x); o[5] = f2bf(b.y); o[6] = f2bf(b.z); o[7] = f2bf(b.w);
  *reinterpret_cast<u16x8*>(dst + i) = o;
}

// ---------------- NT GEMM: C[m][n] = scale * sum_k A[m][k]*B[n][k] ----------------
// BM x 128 tile, BK=64, 4 waves (2x2), 2-phase double-buffered pipeline with
// counted vmcnt (T3/T4), XOR-swizzled LDS (T2, rule-21 both-sides pattern).
// MODE: 0 = plain, 1 = qk^t (skip tc>tr), 2 = pv split-K (z = K-slice of 16 ktiles)
template <int BM, int OUT_BF16, int MODE>
__global__ void __launch_bounds__(256) gemm_nt(const unsigned short* __restrict__ A,
                                               const unsigned short* __restrict__ B,
                                               void* __restrict__ C,
                                               float* __restrict__ P1, float* __restrict__ P2,
                                               float* __restrict__ P3,
                                               int lda, int ldb, int ldc, int K, float scale) {
  constexpr int NLA = BM / 32;  // A global_load_lds per thread per tile
  constexpr int NL = NLA + 4;   // loads in flight for one tile
  constexpr int FM = BM / 32;   // m-fragments per wave

  int tc = blockIdx.x, tr = blockIdx.y;
  if (MODE == 1 && tc > tr) return;
  int kt0 = 0, nt = K >> 6;
  if (MODE == 2) {
    const int s = blockIdx.z;
    const int ltiles = tr + 1;          // causal K-limit in 64-ktiles
    kt0 = s * 16;
    if (kt0 >= ltiles) return;
    nt = min(ltiles, kt0 + 16) - kt0;
  }

  __shared__ __align__(16) unsigned short As[2][BM * 64];
  __shared__ __align__(16) unsigned short Bs[2][128 * 64];

  const int tid = threadIdx.x;
  const int lane = tid & 63;
  const int wid = tid >> 6;
  const int wr = wid >> 1, wc = wid & 1;
  const int l15 = lane & 15;
  const int kq = lane >> 4;

  f32x4 acc[FM][4];
  #pragma unroll
  for (int m = 0; m < FM; ++m)
    #pragma unroll
    for (int n = 0; n < 4; ++n)
      acc[m][n] = (f32x4){0.f, 0.f, 0.f, 0.f};

  const unsigned short* Abase = A + (size_t)tr * BM * lda;
  const unsigned short* Bbase = B + (size_t)tc * 128 * ldb;

  auto stage = [&](int buf, int ktabs) {
    const int k0 = ktabs << 6;
    #pragma unroll
    for (int i = 0; i < NLA; ++i) {
      const int o = (i * 256 + tid) * 16;
      const int os = swz(o);
      const unsigned short* g = Abase + (size_t)(o >> 7) * lda + k0 + ((os >> 4) & 7) * 8;
      __builtin_amdgcn_global_load_lds(
          (const __attribute__((address_space(1))) unsigned int*)g,
          (__attribute__((address_space(3))) unsigned int*)((char*)&As[buf][0] + o), 16, 0, 0);
    }
    #pragma unroll
    for (int i = 0; i < 4; ++i) {
      const int o = (i * 256 + tid) * 16;
      const int os = swz(o);
      const unsigned short* g = Bbase + (size_t)(o >> 7) * ldb + k0 + ((os >> 4) & 7) * 8;
      __builtin_amdgcn_global_load_lds(
          (const __attribute__((address_space(1))) unsigned int*)g,
          (__attribute__((address_space(3))) unsigned int*)((char*)&Bs[buf][0] + o), 16, 0, 0);
    }
  };

  stage(0, kt0);
  int cur = 0;
  for (int kt = 0; kt < nt; ++kt) {
    if (kt + 1 < nt) {
      stage(cur ^ 1, kt0 + kt + 1);  // issue next tile before waiting on current
      wait_vm<NL>();                 // counted: leave next tile's loads in flight
    } else {
      wait_vm<0>();
    }
    __builtin_amdgcn_s_barrier();

    bf16x8 af[FM][2], bv[4][2];
    #pragma unroll
    for (int m = 0; m < FM; ++m)
      #pragma unroll
      for (int ks = 0; ks < 2; ++ks) {
        const int row = wr * (BM / 2) + m * 16 + l15;
        const int o = swz(row * 128 + kq * 16 + ks * 64);
        af[m][ks] = *reinterpret_cast<const bf16x8*>((const char*)&As[cur][0] + o);
      }
    #pragma unroll
    for (int n = 0; n < 4; ++n)
      #pragma unroll
      for (int ks = 0; ks < 2; ++ks) {
        const int row = wc * 64 + n * 16 + l15;
        const int o = swz(row * 128 + kq * 16 + ks * 64);
        bv[n][ks] = *reinterpret_cast<const bf16x8*>((const char*)&Bs[cur][0] + o);
      }
    #pragma unroll
    for (int m = 0; m < FM; ++m)
      #pragma unroll
      for (int n = 0; n < 4; ++n) {
        acc[m][n] = __builtin_amdgcn_mfma_f32_16x16x32_bf16(af[m][0], bv[n][0], acc[m][n], 0, 0, 0);
        acc[m][n] = __builtin_amdgcn_mfma_f32_16x16x32_bf16(af[m][1], bv[n][1], acc[m][n], 0, 0, 0);
      }
    __builtin_amdgcn_s_barrier();
    cur ^= 1;
  }

  // epilogue
  float* fdst = (float*)C;
  int rowoff = 0;
  if (MODE == 2) {
    const int s = blockIdx.z;
    if (s == 1) { fdst = P1; rowoff = 1024; }
    else if (s == 2) { fdst = P2; rowoff = 2048; }
    else if (s == 3) { fdst = P3; rowoff = 3072; }
  }
  const int rbase = tr * BM + wr * (BM / 2) + kq * 4;
  const int cbase = tc * 128 + wc * 64 + l15;
  #pragma unroll
  for (int m = 0; m < FM; ++m)
    #pragma unroll
    for (int n = 0; n < 4; ++n)
      #pragma unroll
      for (int i = 0; i < 4; ++i) {
        const int row = rbase + m * 16 + i;
        const int col = cbase + n * 16;
        float v = acc[m][n][i] * scale;
        if (OUT_BF16)
          ((unsigned short*)C)[(size_t)row * ldc + col] = f2bf(v);
        else
          fdst[(size_t)(row - rowoff) * ldc + col] = v;
      }
}

// ---------------- split-K reduction: out rows 1024.. += partials ----------------
__global__ void __launch_bounds__(256) reduce_kernel(float* __restrict__ out,
                                                     const float* __restrict__ p1,
                                                     const float* __restrict__ p2,
                                                     const float* __restrict__ p3) {
  const int b = blockIdx.x;            // one block per row (rows 1024..4095)
  const size_t e = ((size_t)b * 1024) + threadIdx.x * 4;
  f32x4 acc = *reinterpret_cast<f32x4*>(out + (size_t)1024 * 1024 + e);
  const f32x4 a1 = *reinterpret_cast<const f32x4*>(p1 + e);
  acc += a1;
  if (b >= 1024) acc += *reinterpret_cast<const f32x4*>(p2 + e - (size_t)1024 * 1024);
  if (b >= 2048) acc += *reinterpret_cast<const f32x4*>(p3 + e - (size_t)2048 * 1024);
  *reinterpret_cast<f32x4*>(out + (size_t)1024 * 1024 + e) = acc;
}

// ---------------- in-place causal row softmax over S[SEQ][SEQ] bf16 ----------------
// Only touches columns below the 64-aligned causal boundary (what PV reads).
__global__ void __launch_bounds__(256) softmax_causal(unsigned short* __restrict__ S) {
  const int row = blockIdx.x;
  const int limit = ((row >> 6) + 1) << 6;
  unsigned short* Srow = S + (size_t)row * SEQ;
  const int tid = threadIdx.x;
  const int lane = tid & 63, wid = tid >> 6;

  float vals[16];
  bool act[2];
  #pragma unroll
  for (int i = 0; i < 2; ++i) {
    const int j0 = (tid + i * 256) * 8;
    act[i] = j0 < limit;
    if (act[i]) {
      const uint4 w = *reinterpret_cast<const uint4*>(Srow + j0);
      const unsigned int wb[4] = {w.x, w.y, w.z, w.w};
      #pragma unroll
      for (int e = 0; e < 4; ++e) {
        vals[i * 8 + 2 * e]     = __uint_as_float(wb[e] << 16);
        vals[i * 8 + 2 * e + 1] = __uint_as_float(wb[e] & 0xFFFF0000u);
      }
    } else {
      #pragma unroll
      for (int e = 0; e < 8; ++e) vals[i * 8 + e] = -1e30f;
    }
  }

  float m = -1e30f;
  #pragma unroll
  for (int i = 0; i < 2; ++i)
    #pragma unroll
    for (int e = 0; e < 8; ++e) {
      int j = (tid + i * 256) * 8 + e;
      if (j <= row) m = fmaxf(m, vals[i * 8 + e]);
    }
  #pragma unroll
  for (int off = 32; off > 0; off >>= 1) m = fmaxf(m, __shfl_xor(m, off));
  __shared__ float redm[4], reds[4];
  if (lane == 0) redm[wid] = m;
  __syncthreads();
  m = fmaxf(fmaxf(redm[0], redm[1]), fmaxf(redm[2], redm[3]));

  float s = 0.f;
  float ev[16];
  #pragma unroll
  for (int i = 0; i < 2; ++i)
    #pragma unroll
    for (int e = 0; e < 8; ++e) {
      int j = (tid + i * 256) * 8 + e;
      float ex = (j <= row) ? __expf(vals[i * 8 + e] - m) : 0.f;
      ev[i * 8 + e] = ex;
      s += ex;
    }
  #pragma unroll
  for (int off = 32; off > 0; off >>= 1) s += __shfl_xor(s, off);
  if (lane == 0) reds[wid] = s;
  __syncthreads();
  s = reds[0] + reds[1] + reds[2] + reds[3];
  const float inv = 1.f / s;

  #pragma unroll
  for (int i = 0; i < 2; ++i) {
    if (!act[i]) continue;
    u16x8 o;
    #pragma unroll
    for (int e = 0; e < 8; ++e) o[e] = f2bf(ev[i * 8 + e] * inv);
    *reinterpret_cast<u16x8*>(Srow + (tid + i * 256) * 8) = o;
  }
}

extern "C" void kernel_launch(void* const* d_in, const int* in_sizes, int n_in,
                              void* d_out, int out_size, void* d_ws, size_t ws_size,
                              hipStream_t stream) {
  const float* x  = (const float*)d_in[0];
  const float* Wq = (const float*)d_in[1];
  const float* Wk = (const float*)d_in[2];
  const float* Wv = (const float*)d_in[3];
  float* out = (float*)d_out;

  char* ws = (char*)d_ws;
  const size_t MB = 1u << 20;
  unsigned short* xb   = (unsigned short*)(ws + 0 * MB);   // 8 MB  (dead after proj)
  unsigned short* wqk  = (unsigned short*)(ws + 8 * MB);   // 4 MB  Wq|Wk stacked (dead after proj)
  unsigned short* wvb  = (unsigned short*)(ws + 12 * MB);  // 2 MB  (dead after proj)
  unsigned short* qkb  = (unsigned short*)(ws + 14 * MB);  // 16 MB Q|K [4096][2048] (dead after QK^T)
  unsigned short* vt   = (unsigned short*)(ws + 30 * MB);  // 8 MB  V^T [1024][4096]
  unsigned short* S    = (unsigned short*)(ws + 38 * MB);  // 32 MB (-> P in place)
  // split-K partials reuse the region freed after QK^T:
  float* p1 = (float*)(ws + 0 * MB);    // 12 MB (rows 1024..4095)
  float* p2 = (float*)(ws + 12 * MB);   // 8 MB  (rows 2048..4095)
  float* p3 = (float*)(ws + 20 * MB);   // 4 MB  (rows 3072..4095)

  cvt_kernel<<<SEQ * DIM / 2048, 256, 0, stream>>>(x, xb);
  cvt3_kernel<<<dim3(DIM * DIM / 2048, 3), 256, 0, stream>>>(Wq, Wk, Wv, wqk, wvb);

  // Fused Q|K projection: [4096][2048] = x @ [Wq;Wk]^T
  gemm_nt<128, 1, 0><<<dim3(2048 / 128, SEQ / 128), 256, 0, stream>>>(
      xb, wqk, qkb, nullptr, nullptr, nullptr, DIM, DIM, 2048, DIM, 1.0f);
  // V^T = Wv x^T directly: [DIM][SEQ]
  gemm_nt<128, 1, 0><<<dim3(SEQ / 128, DIM / 128), 256, 0, stream>>>(
      wvb, xb, vt, nullptr, nullptr, nullptr, DIM, DIM, SEQ, DIM, 1.0f);

  // S = (Q K^T) / 32, causal-skipped tiles (Q = qkb cols 0.., K = qkb cols 1024..)
  gemm_nt<128, 1, 1><<<dim3(SEQ / 128, SEQ / 128), 256, 0, stream>>>(
      qkb, qkb + 1024, S, nullptr, nullptr, nullptr, 2048, 2048, SEQ, DIM, 0.03125f);

  softmax_causal<<<SEQ, 256, 0, stream>>>(S);

  // out = P V, split-K: slices of 16 ktiles (1024 K); slice 0 -> out, 1..3 -> partials
  gemm_nt<64, 0, 2><<<dim3(DIM / 128, SEQ / 64, 4), 256, 0, stream>>>(
      S, vt, out, p1, p2, p3, SEQ, SEQ, DIM, SEQ, 1.0f);
  reduce_kernel<<<3072, 256, 0, stream>>>(out, p1, p2, p3);
}

// Round 5
// 141.821 us; speedup vs baseline: 1.7313x; 1.0278x over previous
//
#include <hip/hip_runtime.h>
#include <hip/hip_bf16.h>
#include <stdint.h>

#define SEQ 4096
#define DIM 1024

typedef __attribute__((ext_vector_type(8))) __bf16 bf16x8;
typedef __attribute__((ext_vector_type(4))) float f32x4;
typedef __attribute__((ext_vector_type(8))) unsigned short u16x8;

__device__ __forceinline__ unsigned short f2bf(float f) {
  unsigned int u = __float_as_uint(f);
  u = (u + 0x7FFFu + ((u >> 16) & 1u)) >> 16;
  return (unsigned short)u;
}

// XOR swizzle: spreads the 8 16B-slots of each 128B LDS row across banks.
__device__ __forceinline__ int swz(int o) { return o ^ (((o >> 7) & 7) << 4); }

template <int N> __device__ __forceinline__ void wait_vm() {
  if constexpr (N == 0) asm volatile("s_waitcnt vmcnt(0)" ::: "memory");
  else if constexpr (N == 2) asm volatile("s_waitcnt vmcnt(2)" ::: "memory");
  else if constexpr (N == 4) asm volatile("s_waitcnt vmcnt(4)" ::: "memory");
  else if constexpr (N == 6) asm volatile("s_waitcnt vmcnt(6)" ::: "memory");
  else if constexpr (N == 8) asm volatile("s_waitcnt vmcnt(8)" ::: "memory");
}

// ---------------- f32 -> bf16 convert (8 elems/thread) ----------------
__global__ void __launch_bounds__(256) cvt_kernel(const float* __restrict__ src,
                                                  unsigned short* __restrict__ dst) {
  size_t i = (size_t)(blockIdx.x * 256 + threadIdx.x) * 8;
  float4 a = *reinterpret_cast<const float4*>(src + i);
  float4 b = *reinterpret_cast<const float4*>(src + i + 4);
  u16x8 o;
  o[0] = f2bf(a.x); o[1] = f2bf(a.y); o[2] = f2bf(a.z); o[3] = f2bf(a.w);
  o[4] = f2bf(b.x); o[5] = f2bf(b.y); o[6] = f2bf(b.z); o[7] = f2bf(b.w);
  *reinterpret_cast<u16x8*>(dst + i) = o;
}

__global__ void __launch_bounds__(256) cvt3_kernel(const float* __restrict__ wq,
                                                   const float* __restrict__ wk,
                                                   const float* __restrict__ wv,
                                                   unsigned short* __restrict__ wqk,
                                                   unsigned short* __restrict__ wvb) {
  const int z = blockIdx.y;
  const float* src = (z == 0) ? wq : (z == 1) ? wk : wv;
  unsigned short* dst = (z == 2) ? wvb : wqk + (size_t)z * DIM * DIM;
  size_t i = (size_t)(blockIdx.x * 256 + threadIdx.x) * 8;
  float4 a = *reinterpret_cast<const float4*>(src + i);
  float4 b = *reinterpret_cast<const float4*>(src + i + 4);
  u16x8 o;
  o[0] = f2bf(a.x); o[1] = f2bf(a.y); o[2] = f2bf(a.z); o[3] = f2bf(a.w);
  o[4] = f2bf(b.x); o[5] = f2bf(b.y); o[6] = f2bf(b.z); o[7] = f2bf(b.w);
  *reinterpret_cast<u16x8*>(dst + i) = o;
}

// ============ 256x256 8-phase causal QK^T (m201-style template) ============
// 512 threads = 8 waves (2M x 4N), per-wave 128x64 output. BK=64, K=1024.
// Double-buffered 128 KiB LDS; half-tile staging (B0,B1,A0,A1) spread one
// per phase with 2-phase slack; counted vmcnt(4) once per K-tile; raw
// s_barrier; setprio around pure-MFMA clusters.
__global__ void __launch_bounds__(512) qkt256_kernel(const unsigned short* __restrict__ A,
                                                     const unsigned short* __restrict__ B,
                                                     unsigned short* __restrict__ C) {
  const int tc = blockIdx.x, tr = blockIdx.y;
  if (tc > tr) return;
  constexpr int NT = DIM / 64;  // 16 K-tiles
  constexpr int LDA = 2 * DIM, LDB = 2 * DIM, LDC = SEQ;
  constexpr float SCALE = 0.03125f;

  __shared__ __align__(16) unsigned short As[2][256 * 64];
  __shared__ __align__(16) unsigned short Bs[2][256 * 64];

  const int tid = threadIdx.x;
  const int lane = tid & 63;
  const int wid = tid >> 6;       // 0..7
  const int wr = wid >> 2;        // 0..1
  const int wc = wid & 3;         // 0..3
  const int l15 = lane & 15;
  const int kq = lane >> 4;

  const unsigned short* Abase = A + (size_t)tr * 256 * LDA;
  const unsigned short* Bbase = B + (size_t)tc * 256 * LDB;

  f32x4 acc[8][4];
  #pragma unroll
  for (int m = 0; m < 8; ++m)
    #pragma unroll
    for (int n = 0; n < 4; ++n)
      acc[m][n] = (f32x4){0.f, 0.f, 0.f, 0.f};

  // halves: 0 = B rows 0-127, 1 = B rows 128-255, 2 = A rows 0-127, 3 = A rows 128-255
  auto stage_half = [&](int buf, int kt, int h) {
    const int k0 = kt << 6;
    const bool isB = (h < 2);
    unsigned short* lb = isB ? &Bs[buf][0] : &As[buf][0];
    const unsigned short* gb = isB ? Bbase : Abase;
    #pragma unroll
    for (int i = 0; i < 2; ++i) {
      const int ot = ((h & 1) << 14) + ((i * 512 + tid) << 4);  // byte off in [256][64] tile
      const int row = ot >> 7;
      const int cs = (swz(ot) >> 4) & 7;
      const unsigned short* g = gb + (size_t)row * LDA + k0 + cs * 8;
      __builtin_amdgcn_global_load_lds(
          (const __attribute__((address_space(1))) unsigned int*)g,
          (__attribute__((address_space(3))) unsigned int*)((char*)lb + ot), 16, 0, 0);
    }
  };

  bf16x8 a[4][2], bn0[2][2], bn1[2][2];

  auto read_A = [&](int b, int mi) {
    #pragma unroll
    for (int f = 0; f < 4; ++f) {
      const int row = wr * 128 + mi * 64 + f * 16 + l15;
      #pragma unroll
      for (int ks = 0; ks < 2; ++ks)
        a[f][ks] = *reinterpret_cast<const bf16x8*>(
            (const char*)&As[b][0] + swz(row * 128 + kq * 16 + ks * 64));
    }
  };
  auto read_B = [&](int b, int n, bf16x8 (*dst)[2]) {
    #pragma unroll
    for (int g = 0; g < 2; ++g) {
      const int row = wc * 64 + n * 32 + g * 16 + l15;
      #pragma unroll
      for (int ks = 0; ks < 2; ++ks)
        dst[g][ks] = *reinterpret_cast<const bf16x8*>(
            (const char*)&Bs[b][0] + swz(row * 128 + kq * 16 + ks * 64));
    }
  };
  auto mma_q = [&](int mi, int n, bf16x8 (*bb)[2]) {
    #pragma unroll
    for (int f = 0; f < 4; ++f)
      #pragma unroll
      for (int g = 0; g < 2; ++g) {
        acc[mi * 4 + f][n * 2 + g] =
            __builtin_amdgcn_mfma_f32_16x16x32_bf16(a[f][0], bb[g][0], acc[mi * 4 + f][n * 2 + g], 0, 0, 0);
        acc[mi * 4 + f][n * 2 + g] =
            __builtin_amdgcn_mfma_f32_16x16x32_bf16(a[f][1], bb[g][1], acc[mi * 4 + f][n * 2 + g], 0, 0, 0);
      }
  };

  // Prologue: tile0 fully + B halves of tile1 (matches steady-state issue order)
  stage_half(0, 0, 0); stage_half(0, 0, 1); stage_half(0, 0, 2); stage_half(0, 0, 3);
  stage_half(1, 1, 0); stage_half(1, 1, 1);
  wait_vm<4>();  // tile0's 8 loads landed; tile1's B halves stay in flight
  __builtin_amdgcn_s_barrier();

  #pragma unroll 1
  for (int kt = 0; kt < NT; ++kt) {
    const int b = kt & 1;
    const bool pf1 = (kt + 1 < NT);
    const bool pf2 = (kt + 2 < NT);
    // ---- phase 0: quadrant (mi0, n0) ----
    read_A(b, 0);
    read_B(b, 0, bn0);
    if (pf1) stage_half(b ^ 1, kt + 1, 2);  // A0(kt+1)
    __builtin_amdgcn_s_barrier();
    __builtin_amdgcn_s_setprio(1);
    mma_q(0, 0, bn0);
    __builtin_amdgcn_s_setprio(0);
    __builtin_amdgcn_s_barrier();
    // ---- phase 1: quadrant (mi0, n1) ----
    read_B(b, 1, bn1);
    if (pf1) stage_half(b ^ 1, kt + 1, 3);  // A1(kt+1)
    __builtin_amdgcn_s_barrier();
    __builtin_amdgcn_s_setprio(1);
    mma_q(0, 1, bn1);
    __builtin_amdgcn_s_setprio(0);
    __builtin_amdgcn_s_barrier();
    // ---- phase 2: quadrant (mi1, n1) ----
    read_A(b, 1);
    if (pf2) stage_half(b, kt + 2, 0);      // B0(kt+2) (Bs[b] last read in phase 1)
    __builtin_amdgcn_s_barrier();
    __builtin_amdgcn_s_setprio(1);
    mma_q(1, 1, bn1);
    __builtin_amdgcn_s_setprio(0);
    __builtin_amdgcn_s_barrier();
    // ---- phase 3: quadrant (mi1, n0) ----
    if (pf2) stage_half(b, kt + 2, 1);      // B1(kt+2)
    if (pf1) {
      if (pf2) wait_vm<4>();                // tile kt+1 fully landed; kt+2's B halves fly
      else wait_vm<0>();
    }
    __builtin_amdgcn_s_barrier();
    __builtin_amdgcn_s_setprio(1);
    mma_q(1, 0, bn0);
    __builtin_amdgcn_s_setprio(0);
    __builtin_amdgcn_s_barrier();
  }

  const int rb = tr * 256 + wr * 128 + kq * 4;
  const int cb = tc * 256 + wc * 64 + l15;
  #pragma unroll
  for (int am = 0; am < 8; ++am)
    #pragma unroll
    for (int an = 0; an < 4; ++an)
      #pragma unroll
      for (int i = 0; i < 4; ++i)
        C[(size_t)(rb + am * 16 + i) * LDC + cb + an * 16] = f2bf(acc[am][an][i] * SCALE);
}

// ---------------- NT GEMM (128-tile 2-phase; proj + PV split-K) ----------------
template <int BM, int OUT_BF16, int MODE>
__global__ void __launch_bounds__(256) gemm_nt(const unsigned short* __restrict__ A,
                                               const unsigned short* __restrict__ B,
                                               void* __restrict__ C,
                                               float* __restrict__ P1, float* __restrict__ P2,
                                               float* __restrict__ P3,
                                               int lda, int ldb, int ldc, int K, float scale) {
  constexpr int NLA = BM / 32;
  constexpr int NL = NLA + 4;
  constexpr int FM = BM / 32;

  int tc = blockIdx.x, tr = blockIdx.y;
  int kt0 = 0, nt = K >> 6;
  if (MODE == 2) {
    const int s = blockIdx.z;
    const int ltiles = tr + 1;
    kt0 = s * 16;
    if (kt0 >= ltiles) return;
    nt = min(ltiles, kt0 + 16) - kt0;
  }

  __shared__ __align__(16) unsigned short As[2][BM * 64];
  __shared__ __align__(16) unsigned short Bs[2][128 * 64];

  const int tid = threadIdx.x;
  const int lane = tid & 63;
  const int wid = tid >> 6;
  const int wr = wid >> 1, wc = wid & 1;
  const int l15 = lane & 15;
  const int kq = lane >> 4;

  f32x4 acc[FM][4];
  #pragma unroll
  for (int m = 0; m < FM; ++m)
    #pragma unroll
    for (int n = 0; n < 4; ++n)
      acc[m][n] = (f32x4){0.f, 0.f, 0.f, 0.f};

  const unsigned short* Abase = A + (size_t)tr * BM * lda;
  const unsigned short* Bbase = B + (size_t)tc * 128 * ldb;

  auto stage = [&](int buf, int ktabs) {
    const int k0 = ktabs << 6;
    #pragma unroll
    for (int i = 0; i < NLA; ++i) {
      const int o = (i * 256 + tid) * 16;
      const int os = swz(o);
      const unsigned short* g = Abase + (size_t)(o >> 7) * lda + k0 + ((os >> 4) & 7) * 8;
      __builtin_amdgcn_global_load_lds(
          (const __attribute__((address_space(1))) unsigned int*)g,
          (__attribute__((address_space(3))) unsigned int*)((char*)&As[buf][0] + o), 16, 0, 0);
    }
    #pragma unroll
    for (int i = 0; i < 4; ++i) {
      const int o = (i * 256 + tid) * 16;
      const int os = swz(o);
      const unsigned short* g = Bbase + (size_t)(o >> 7) * ldb + k0 + ((os >> 4) & 7) * 8;
      __builtin_amdgcn_global_load_lds(
          (const __attribute__((address_space(1))) unsigned int*)g,
          (__attribute__((address_space(3))) unsigned int*)((char*)&Bs[buf][0] + o), 16, 0, 0);
    }
  };

  stage(0, kt0);
  int cur = 0;
  for (int kt = 0; kt < nt; ++kt) {
    if (kt + 1 < nt) {
      stage(cur ^ 1, kt0 + kt + 1);
      wait_vm<NL>();
    } else {
      wait_vm<0>();
    }
    __builtin_amdgcn_s_barrier();

    bf16x8 af[FM][2], bv[4][2];
    #pragma unroll
    for (int m = 0; m < FM; ++m)
      #pragma unroll
      for (int ks = 0; ks < 2; ++ks) {
        const int row = wr * (BM / 2) + m * 16 + l15;
        const int o = swz(row * 128 + kq * 16 + ks * 64);
        af[m][ks] = *reinterpret_cast<const bf16x8*>((const char*)&As[cur][0] + o);
      }
    #pragma unroll
    for (int n = 0; n < 4; ++n)
      #pragma unroll
      for (int ks = 0; ks < 2; ++ks) {
        const int row = wc * 64 + n * 16 + l15;
        const int o = swz(row * 128 + kq * 16 + ks * 64);
        bv[n][ks] = *reinterpret_cast<const bf16x8*>((const char*)&Bs[cur][0] + o);
      }
    #pragma unroll
    for (int m = 0; m < FM; ++m)
      #pragma unroll
      for (int n = 0; n < 4; ++n) {
        acc[m][n] = __builtin_amdgcn_mfma_f32_16x16x32_bf16(af[m][0], bv[n][0], acc[m][n], 0, 0, 0);
        acc[m][n] = __builtin_amdgcn_mfma_f32_16x16x32_bf16(af[m][1], bv[n][1], acc[m][n], 0, 0, 0);
      }
    __builtin_amdgcn_s_barrier();
    cur ^= 1;
  }

  float* fdst = (float*)C;
  int rowoff = 0;
  if (MODE == 2) {
    const int s = blockIdx.z;
    if (s == 1) { fdst = P1; rowoff = 1024; }
    else if (s == 2) { fdst = P2; rowoff = 2048; }
    else if (s == 3) { fdst = P3; rowoff = 3072; }
  }
  const int rbase = tr * BM + wr * (BM / 2) + kq * 4;
  const int cbase = tc * 128 + wc * 64 + l15;
  #pragma unroll
  for (int m = 0; m < FM; ++m)
    #pragma unroll
    for (int n = 0; n < 4; ++n)
      #pragma unroll
      for (int i = 0; i < 4; ++i) {
        const int row = rbase + m * 16 + i;
        const int col = cbase + n * 16;
        float v = acc[m][n][i] * scale;
        if (OUT_BF16)
          ((unsigned short*)C)[(size_t)row * ldc + col] = f2bf(v);
        else
          fdst[(size_t)(row - rowoff) * ldc + col] = v;
      }
}

// ---------------- split-K reduction ----------------
__global__ void __launch_bounds__(256) reduce_kernel(float* __restrict__ out,
                                                     const float* __restrict__ p1,
                                                     const float* __restrict__ p2,
                                                     const float* __restrict__ p3) {
  const int b = blockIdx.x;
  const size_t e = ((size_t)b * 1024) + threadIdx.x * 4;
  f32x4 acc = *reinterpret_cast<f32x4*>(out + (size_t)1024 * 1024 + e);
  acc += *reinterpret_cast<const f32x4*>(p1 + e);
  if (b >= 1024) acc += *reinterpret_cast<const f32x4*>(p2 + e - (size_t)1024 * 1024);
  if (b >= 2048) acc += *reinterpret_cast<const f32x4*>(p3 + e - (size_t)2048 * 1024);
  *reinterpret_cast<f32x4*>(out + (size_t)1024 * 1024 + e) = acc;
}

// ---------------- in-place causal row softmax ----------------
__global__ void __launch_bounds__(256) softmax_causal(unsigned short* __restrict__ S) {
  const int row = blockIdx.x;
  const int limit = ((row >> 6) + 1) << 6;
  unsigned short* Srow = S + (size_t)row * SEQ;
  const int tid = threadIdx.x;
  const int lane = tid & 63, wid = tid >> 6;

  float vals[16];
  bool act[2];
  #pragma unroll
  for (int i = 0; i < 2; ++i) {
    const int j0 = (tid + i * 256) * 8;
    act[i] = j0 < limit;
    if (act[i]) {
      const uint4 w = *reinterpret_cast<const uint4*>(Srow + j0);
      const unsigned int wb[4] = {w.x, w.y, w.z, w.w};
      #pragma unroll
      for (int e = 0; e < 4; ++e) {
        vals[i * 8 + 2 * e]     = __uint_as_float(wb[e] << 16);
        vals[i * 8 + 2 * e + 1] = __uint_as_float(wb[e] & 0xFFFF0000u);
      }
    } else {
      #pragma unroll
      for (int e = 0; e < 8; ++e) vals[i * 8 + e] = -1e30f;
    }
  }

  float m = -1e30f;
  #pragma unroll
  for (int i = 0; i < 2; ++i)
    #pragma unroll
    for (int e = 0; e < 8; ++e) {
      int j = (tid + i * 256) * 8 + e;
      if (j <= row) m = fmaxf(m, vals[i * 8 + e]);
    }
  #pragma unroll
  for (int off = 32; off > 0; off >>= 1) m = fmaxf(m, __shfl_xor(m, off));
  __shared__ float redm[4], reds[4];
  if (lane == 0) redm[wid] = m;
  __syncthreads();
  m = fmaxf(fmaxf(redm[0], redm[1]), fmaxf(redm[2], redm[3]));

  float s = 0.f;
  float ev[16];
  #pragma unroll
  for (int i = 0; i < 2; ++i)
    #pragma unroll
    for (int e = 0; e < 8; ++e) {
      int j = (tid + i * 256) * 8 + e;
      float ex = (j <= row) ? __expf(vals[i * 8 + e] - m) : 0.f;
      ev[i * 8 + e] = ex;
      s += ex;
    }
  #pragma unroll
  for (int off = 32; off > 0; off >>= 1) s += __shfl_xor(s, off);
  if (lane == 0) reds[wid] = s;
  __syncthreads();
  s = reds[0] + reds[1] + reds[2] + reds[3];
  const float inv = 1.f / s;

  #pragma unroll
  for (int i = 0; i < 2; ++i) {
    if (!act[i]) continue;
    u16x8 o;
    #pragma unroll
    for (int e = 0; e < 8; ++e) o[e] = f2bf(ev[i * 8 + e] * inv);
    *reinterpret_cast<u16x8*>(Srow + (tid + i * 256) * 8) = o;
  }
}

extern "C" void kernel_launch(void* const* d_in, const int* in_sizes, int n_in,
                              void* d_out, int out_size, void* d_ws, size_t ws_size,
                              hipStream_t stream) {
  const float* x  = (const float*)d_in[0];
  const float* Wq = (const float*)d_in[1];
  const float* Wk = (const float*)d_in[2];
  const float* Wv = (const float*)d_in[3];
  float* out = (float*)d_out;

  char* ws = (char*)d_ws;
  const size_t MB = 1u << 20;
  unsigned short* xb   = (unsigned short*)(ws + 0 * MB);   // 8 MB  (dead after proj)
  unsigned short* wqk  = (unsigned short*)(ws + 8 * MB);   // 4 MB
  unsigned short* wvb  = (unsigned short*)(ws + 12 * MB);  // 2 MB
  unsigned short* qkb  = (unsigned short*)(ws + 14 * MB);  // 16 MB Q|K [4096][2048]
  unsigned short* vt   = (unsigned short*)(ws + 30 * MB);  // 8 MB  V^T [1024][4096]
  unsigned short* S    = (unsigned short*)(ws + 38 * MB);  // 32 MB (-> P in place)
  float* p1 = (float*)(ws + 0 * MB);    // 12 MB
  float* p2 = (float*)(ws + 12 * MB);   // 8 MB
  float* p3 = (float*)(ws + 20 * MB);   // 4 MB

  cvt_kernel<<<SEQ * DIM / 2048, 256, 0, stream>>>(x, xb);
  cvt3_kernel<<<dim3(DIM * DIM / 2048, 3), 256, 0, stream>>>(Wq, Wk, Wv, wqk, wvb);

  gemm_nt<128, 1, 0><<<dim3(2048 / 128, SEQ / 128), 256, 0, stream>>>(
      xb, wqk, qkb, nullptr, nullptr, nullptr, DIM, DIM, 2048, DIM, 1.0f);
  gemm_nt<128, 1, 0><<<dim3(SEQ / 128, DIM / 128), 256, 0, stream>>>(
      wvb, xb, vt, nullptr, nullptr, nullptr, DIM, DIM, SEQ, DIM, 1.0f);

  // S = (Q K^T) / 32 — 256² 8-phase template, causal-skipped tiles
  qkt256_kernel<<<dim3(SEQ / 256, SEQ / 256), 512, 0, stream>>>(qkb, qkb + 1024, S);

  softmax_causal<<<SEQ, 256, 0, stream>>>(S);

  gemm_nt<64, 0, 2><<<dim3(DIM / 128, SEQ / 64, 4), 256, 0, stream>>>(
      S, vt, out, p1, p2, p3, SEQ, SEQ, DIM, SEQ, 1.0f);
  reduce_kernel<<<3072, 256, 0, stream>>>(out, p1, p2, p3);
}